// Round 11
// baseline (124.535 us; speedup 1.0000x reference)
//
#include <hip/hip_runtime.h>
#include <hip/hip_bf16.h>

#define N_TOK 4096
#define NH 8
#define HD 32
#define CDIM 256
#define QKV_N 768
#define VT_STRIDE 4128   // padded global V^T row: breaks power-of-2 channel/set alias
#define XB_STRIDE 272    // padded rows for xb/ob/weight scratch (breaks 512B stride)
#define SCALE_F 0.17677669529663687f
#define LOG2E   1.4426950408889634f

typedef float  f32x4  __attribute__((ext_vector_type(4)));
typedef int    i32x4  __attribute__((ext_vector_type(4)));
typedef short  s16x4  __attribute__((ext_vector_type(4)));
typedef __bf16 bf16x8 __attribute__((ext_vector_type(8)));

union FragI { i32x4 i; bf16x8 b; };

// pack two f32 into bf16x2 by truncation: ONE v_perm_b32.
__device__ inline int pack_bf16_trunc(float a, float b) {
  return (int)__builtin_amdgcn_perm(__builtin_bit_cast(unsigned, b),
                                    __builtin_bit_cast(unsigned, a),
                                    0x07060302u);
}

// ---------------------------------------------------------------------------
// fused prep: x->bf16 (rows padded to 272), qkv_w->bf16 (Q rows pre-scaled by
// SCALE*log2e), proj_w->bf16, keep-mask -> bias/keepi.
#define SEG_X 1048576
#define SEG_W (SEG_X + 196608)
#define SEG_P (SEG_W + 65536)
#define SEG_M (SEG_P + 4096)
__global__ __launch_bounds__(256) void fused_prep(const float* __restrict__ x,
                                                  const float* __restrict__ qkv_w,
                                                  const float* __restrict__ proj_w,
                                                  const float* __restrict__ dbz,
                                                  __bf16* __restrict__ xb,
                                                  __bf16* __restrict__ wqkvb,
                                                  __bf16* __restrict__ wprojb,
                                                  float* __restrict__ bias,
                                                  int* __restrict__ keepi) {
  int gid = blockIdx.x * 256 + threadIdx.x;
  if (gid < SEG_X) {
    xb[(gid >> 8) * XB_STRIDE + (gid & 255)] = (__bf16)x[gid];
  } else if (gid < SEG_W) {
    int i = gid - SEG_X;
    float s = ((i >> 8) < 256) ? (SCALE_F * LOG2E) : 1.0f;   // Q output rows
    wqkvb[(i >> 8) * XB_STRIDE + (i & 255)] = (__bf16)(qkv_w[i] * s);
  } else if (gid < SEG_P) {
    int i = gid - SEG_W;
    wprojb[(i >> 8) * XB_STRIDE + (i & 255)] = (__bf16)proj_w[i];
  } else if (gid < SEG_M) {
    int n = gid - SEG_P;
    int t = n >> 10, rc = n & 1023, r = rc >> 5, c = rc & 31;
    bool keep = false;
    #pragma unroll
    for (int dr = -1; dr <= 1; dr++)
      #pragma unroll
      for (int dc = -1; dc <= 1; dc++) {
        int rr = r + dr, cc = c + dc;
        if (rr >= 0 && rr < 32 && cc >= 0 && cc < 32)
          keep = keep || (dbz[t * 1024 + rr * 32 + cc] >= 15.0f);
      }
    bias[n]  = keep ? 0.0f : -30000.0f;   // exp2(s-30000) == 0 exactly
    keepi[n] = keep ? 1 : 0;
  }
}

// ---------------------------------------------------------------------------
// QKV GEMM, operand-swapped (D[channel][token]), software-pipelined k-loop.
// q,k -> [h][n][d]; v -> [h][d][VT_STRIDE] with keys SIGMA-PERMUTED within
// each 32-key group so the attention V fragment is ONE contiguous dwordx4.
__global__ __launch_bounds__(256) void qkv_gemm(const __bf16* __restrict__ xb,
                                                const __bf16* __restrict__ wb,
                                                __bf16* __restrict__ qb,
                                                __bf16* __restrict__ kb,
                                                __bf16* __restrict__ vt) {
  int wave = threadIdx.x >> 6, lane = threadIdx.x & 63;
  int quad = lane >> 4, l16 = lane & 15;
  int m0 = blockIdx.x * 64 + wave * 16;   // tokens
  int n0 = blockIdx.y * 64;               // output channels

  const __bf16* xrow = xb + (size_t)(m0 + l16) * XB_STRIDE + quad * 8;
  const __bf16* wrow = wb + (size_t)(n0 + l16) * XB_STRIDE + quad * 8;

  FragI xc, wc[4];
  xc.i = *(const i32x4*)(xrow);
  #pragma unroll
  for (int nt = 0; nt < 4; nt++)
    wc[nt].i = *(const i32x4*)(wrow + (size_t)nt * 16 * XB_STRIDE);

  f32x4 acc[4] = {};
  for (int kk = 0; kk < CDIM; kk += 32) {
    int kn = (kk + 32 < CDIM) ? kk + 32 : 0;      // last prefetch unused
    FragI xn, wn[4];
    xn.i = *(const i32x4*)(xrow + kn);
    #pragma unroll
    for (int nt = 0; nt < 4; nt++)
      wn[nt].i = *(const i32x4*)(wrow + (size_t)nt * 16 * XB_STRIDE + kn);
    #pragma unroll
    for (int nt = 0; nt < 4; nt++)
      acc[nt] = __builtin_amdgcn_mfma_f32_16x16x32_bf16(wc[nt].b, xc.b, acc[nt], 0, 0, 0);
    xc = xn;
    #pragma unroll
    for (int nt = 0; nt < 4; nt++) wc[nt] = wn[nt];
  }
  int m = m0 + l16;
  // sigma-permuted token index within its 32-key group (for V only)
  int mperm = (m & ~31) + ((l16 >> 2) * 8) + (l16 & 3) + ((m & 16) ? 4 : 0);
  #pragma unroll
  for (int nt = 0; nt < 4; nt++) {
    int cbase = n0 + nt * 16 + quad * 4;       // 4 consecutive channels
    int which = cbase >> 8, rem = cbase & 255, hd = rem >> 5, d0 = rem & 31;
    if (which < 2) {
      union { s16x4 s; __bf16 h[4]; } u;
      #pragma unroll
      for (int r = 0; r < 4; r++) u.h[r] = (__bf16)acc[nt][r];
      __bf16* dst = (which == 0 ? qb : kb) + ((size_t)hd * N_TOK + m) * HD + d0;
      *(s16x4*)dst = u.s;
    } else {
      #pragma unroll
      for (int r = 0; r < 4; r++)
        vt[(size_t)(hd * HD + d0 + r) * VT_STRIDE + mperm] = (__bf16)acc[nt][r];
    }
  }
}

// ---------------------------------------------------------------------------
// Attention v10: OCCUPANCY round. Block = 32 queries (2 q-groups/wave), so
// per-wave register state shrinks to ~125 <= 128 and __launch_bounds__(256,4)
// is honest: 1024 blocks = 4 blocks/CU = 4 waves/SIMD (2x R9). Waves split
// keys 4-ways (wave w: keys w*32+128t, 32 iters). Ping-pong operand buffers
// (no copies, no vmcnt drain), sigma-permuted V (one dwordx4/lane), no-max
// exp2 softmax with bias in the S-MFMA C operand, l via ones-MFMA,
// truncation-pack P.
__global__ __launch_bounds__(256, 4) void attn_kernel(const __bf16* __restrict__ qb,
                                                      const __bf16* __restrict__ kb,
                                                      const __bf16* __restrict__ vt,
                                                      const float* __restrict__ bias,
                                                      __bf16* __restrict__ ob) {
  __shared__ float red_o[4][32][34];   // 17.4KB; 4 blocks/CU -> 72KB/CU OK
  __shared__ float red_l[4][32];

  int b = blockIdx.x;
  int head = b & 7, qx = b >> 3;       // 1024 blocks; head%8 -> XCD affinity
  int wave = threadIdx.x >> 6, lane = threadIdx.x & 63;
  int quad = lane >> 4, l16 = lane & 15;
  int q0 = qx * 32;

  const __bf16* qh = qb + (size_t)head * N_TOK * HD;
  const __bf16* kh = kb + (size_t)head * N_TOK * HD;
  const __bf16* vh = vt + (size_t)head * HD * VT_STRIDE;

  FragI qf[2];
  #pragma unroll
  for (int g = 0; g < 2; g++)
    qf[g].i = *(const i32x4*)(qh + (size_t)(q0 + g * 16 + l16) * HD + quad * 8);

  FragI ones;
  #pragma unroll
  for (int j = 0; j < 8; j++) ones.b[j] = (__bf16)1.0f;

  f32x4 o_lo[2] = {}, o_hi[2] = {}, lacc[2] = {};

  // ping-pong operand buffers
  FragI ka[2], kx[2], vlo[2], vhi[2];
  f32x4 ba[2], bb[2];
  {
    int k0 = wave * 32;
    ka[0].i  = *(const i32x4*)(kh + (size_t)(k0 + l16) * HD + quad * 8);
    kx[0].i  = *(const i32x4*)(kh + (size_t)(k0 + 16 + l16) * HD + quad * 8);
    ba[0] = *(const f32x4*)(bias + k0 + quad * 4);
    bb[0] = *(const f32x4*)(bias + k0 + 16 + quad * 4);
    vlo[0].i = *(const i32x4*)(vh + (size_t)l16 * VT_STRIDE + k0 + quad * 8);
    vhi[0].i = *(const i32x4*)(vh + (size_t)(16 + l16) * VT_STRIDE + k0 + quad * 8);
  }

  #pragma unroll 4
  for (int t = 0; t < 32; t++) {
    int cur = t & 1, nxt = cur ^ 1;
    int kn = (t < 31) ? wave * 32 + (t + 1) * 128 : wave * 32;  // wrap unused

    // next-iteration loads into the OTHER buffer (renamed regs, no copies)
    ka[nxt].i  = *(const i32x4*)(kh + (size_t)(kn + l16) * HD + quad * 8);
    kx[nxt].i  = *(const i32x4*)(kh + (size_t)(kn + 16 + l16) * HD + quad * 8);
    ba[nxt] = *(const f32x4*)(bias + kn + quad * 4);
    bb[nxt] = *(const f32x4*)(bias + kn + 16 + quad * 4);
    vlo[nxt].i = *(const i32x4*)(vh + (size_t)l16 * VT_STRIDE + kn + quad * 8);
    vhi[nxt].i = *(const i32x4*)(vh + (size_t)(16 + l16) * VT_STRIDE + kn + quad * 8);

    // S^T per q-group: D[key][q] init = bias(key)
    f32x4 sa[2], sb[2];
    #pragma unroll
    for (int g = 0; g < 2; g++) {
      sa[g] = __builtin_amdgcn_mfma_f32_16x16x32_bf16(ka[cur].b, qf[g].b, ba[cur], 0, 0, 0);
      sb[g] = __builtin_amdgcn_mfma_f32_16x16x32_bf16(kx[cur].b, qf[g].b, bb[cur], 0, 0, 0);
    }

    FragI pf[2];
    #pragma unroll
    for (int g = 0; g < 2; g++) {
      float e0 = __builtin_amdgcn_exp2f(sa[g][0]);
      float e1 = __builtin_amdgcn_exp2f(sa[g][1]);
      float e2 = __builtin_amdgcn_exp2f(sa[g][2]);
      float e3 = __builtin_amdgcn_exp2f(sa[g][3]);
      float e4 = __builtin_amdgcn_exp2f(sb[g][0]);
      float e5 = __builtin_amdgcn_exp2f(sb[g][1]);
      float e6 = __builtin_amdgcn_exp2f(sb[g][2]);
      float e7 = __builtin_amdgcn_exp2f(sb[g][3]);
      pf[g].i[0] = pack_bf16_trunc(e0, e1);
      pf[g].i[1] = pack_bf16_trunc(e2, e3);
      pf[g].i[2] = pack_bf16_trunc(e4, e5);
      pf[g].i[3] = pack_bf16_trunc(e6, e7);
    }

    #pragma unroll
    for (int g = 0; g < 2; g++) {
      o_lo[g] = __builtin_amdgcn_mfma_f32_16x16x32_bf16(vlo[cur].b, pf[g].b, o_lo[g], 0, 0, 0);
      o_hi[g] = __builtin_amdgcn_mfma_f32_16x16x32_bf16(vhi[cur].b, pf[g].b, o_hi[g], 0, 0, 0);
      lacc[g] = __builtin_amdgcn_mfma_f32_16x16x32_bf16(ones.b, pf[g].b, lacc[g], 0, 0, 0);
    }
  }

  // ---- cross-wave reduction (one LDS round-trip) ----
  #pragma unroll
  for (int g = 0; g < 2; g++) {
    int q = g * 16 + l16;
    #pragma unroll
    for (int r = 0; r < 4; r++) {
      red_o[wave][q][quad * 4 + r]      = o_lo[g][r];
      red_o[wave][q][16 + quad * 4 + r] = o_hi[g][r];
    }
    if (quad == 0) red_l[wave][q] = lacc[g][0];  // all rows equal = l(q)
  }
  __syncthreads();

  // waves 0,1 reduce q-group g = wave (16 queries each)
  if (wave < 2) {
    int q = wave * 16 + l16;
    float lt = red_l[0][q] + red_l[1][q] + red_l[2][q] + red_l[3][q];
    float inv = 1.0f / lt;
    f32x4 slo = {0.f, 0.f, 0.f, 0.f}, shi = {0.f, 0.f, 0.f, 0.f};
    #pragma unroll
    for (int src = 0; src < 4; src++) {
      #pragma unroll
      for (int r = 0; r < 4; r++) {
        slo[r] += red_o[src][q][quad * 4 + r];
        shi[r] += red_o[src][q][16 + quad * 4 + r];
      }
    }
    union { s16x4 s; __bf16 h[4]; } u1, u2;
    #pragma unroll
    for (int r = 0; r < 4; r++) {
      u1.h[r] = (__bf16)(slo[r] * inv);
      u2.h[r] = (__bf16)(shi[r] * inv);
    }
    __bf16* orow = ob + (size_t)(q0 + q) * XB_STRIDE + head * HD;
    *(s16x4*)(orow + quad * 4)      = u1.s;
    *(s16x4*)(orow + 16 + quad * 4) = u2.s;
  }
}

// ---------------------------------------------------------------------------
// Output projection (pipelined): out = (keep ? attn@Wp^T + b : 0) + x
__global__ __launch_bounds__(256) void proj_gemm(const __bf16* __restrict__ ob,
                                                 const __bf16* __restrict__ wb,
                                                 const float* __restrict__ pb,
                                                 const int* __restrict__ keepi,
                                                 const float* __restrict__ x,
                                                 float* __restrict__ out) {
  int wave = threadIdx.x >> 6, lane = threadIdx.x & 63;
  int quad = lane >> 4, l16 = lane & 15;
  int m0 = blockIdx.x * 64 + wave * 16;
  int n0 = blockIdx.y * 64;

  const __bf16* arow = ob + (size_t)(m0 + l16) * XB_STRIDE + quad * 8;
  const __bf16* wrow = wb + (size_t)(n0 + l16) * XB_STRIDE + quad * 8;

  FragI ac, wc[4];
  ac.i = *(const i32x4*)(arow);
  #pragma unroll
  for (int nt = 0; nt < 4; nt++)
    wc[nt].i = *(const i32x4*)(wrow + (size_t)nt * 16 * XB_STRIDE);

  f32x4 acc[4] = {};
  for (int kk = 0; kk < CDIM; kk += 32) {
    int kn = (kk + 32 < CDIM) ? kk + 32 : 0;
    FragI an, wn[4];
    an.i = *(const i32x4*)(arow + kn);
    #pragma unroll
    for (int nt = 0; nt < 4; nt++)
      wn[nt].i = *(const i32x4*)(wrow + (size_t)nt * 16 * XB_STRIDE + kn);
    #pragma unroll
    for (int nt = 0; nt < 4; nt++)
      acc[nt] = __builtin_amdgcn_mfma_f32_16x16x32_bf16(wc[nt].b, ac.b, acc[nt], 0, 0, 0);
    ac = an;
    #pragma unroll
    for (int nt = 0; nt < 4; nt++) wc[nt] = wn[nt];
  }
  // D[channel][token]: row = channel quad*4+r, col = token l16
  int m = m0 + l16;
  int keep = keepi[m];
  #pragma unroll
  for (int nt = 0; nt < 4; nt++) {
    int c0 = n0 + nt * 16 + quad * 4;
    #pragma unroll
    for (int r = 0; r < 4; r++) {
      float v = acc[nt][r] + pb[c0 + r];
      v = keep ? v : 0.0f;
      out[(size_t)m * CDIM + c0 + r] = v + x[(size_t)m * CDIM + c0 + r];
    }
  }
}

// ---------------------------------------------------------------------------
extern "C" void kernel_launch(void* const* d_in, const int* in_sizes, int n_in,
                              void* d_out, int out_size, void* d_ws, size_t ws_size,
                              hipStream_t stream) {
  const float* x      = (const float*)d_in[0];
  const float* dbz    = (const float*)d_in[1];
  const float* qkv_w  = (const float*)d_in[2];
  const float* proj_w = (const float*)d_in[3];
  const float* proj_b = (const float*)d_in[4];
  float* out = (float*)d_out;

  char* w = (char*)d_ws;
  __bf16* xb     = (__bf16*)(w);                        // 4096x272x2 = 2.23MB
  __bf16* qb     = (__bf16*)(w + (3u << 20));           // 2MB
  __bf16* kb     = (__bf16*)(w + (5u << 20));           // 2MB
  __bf16* vt     = (__bf16*)(w + (7u << 20));           // 8*32*4128*2 = 2.02MB
  __bf16* ob     = (__bf16*)(w + (9u << 20) + (512u << 10));  // 2.23MB
  __bf16* wqkvb  = (__bf16*)(w + (12u << 20));          // 768x272x2 = 417KB
  __bf16* wprojb = (__bf16*)(w + (12u << 20) + (512u << 10)); // 139KB
  float*  bias   = (float*)(w + (13u << 20));           // 16KB
  int*    keepi  = (int*)(w + (13u << 20) + 16384);     // 16KB

  fused_prep<<<dim3(SEG_M / 256), dim3(256), 0, stream>>>(
      x, qkv_w, proj_w, dbz, xb, wqkvb, wprojb, bias, keepi);
  qkv_gemm<<<dim3(N_TOK / 64, QKV_N / 64), dim3(256), 0, stream>>>(
      xb, wqkvb, qb, kb, vt);
  attn_kernel<<<dim3((N_TOK / 32) * NH), dim3(256), 0, stream>>>(
      qb, kb, vt, bias, ob);
  proj_gemm<<<dim3(N_TOK / 64, CDIM / 64), dim3(256), 0, stream>>>(
      ob, wprojb, proj_b, keepi, x, out);
}

// Round 12
// 107.905 us; speedup vs baseline: 1.1541x; 1.1541x over previous
//
#include <hip/hip_runtime.h>
#include <hip/hip_bf16.h>

#define N_TOK 4096
#define NH 8
#define HD 32
#define CDIM 256
#define QKV_N 768
#define VT_STRIDE 4128   // padded global V^T row: breaks power-of-2 channel/set alias
#define XB_STRIDE 272    // padded rows for xb/ob/weight scratch (breaks 512B stride)
#define SCALE_F 0.17677669529663687f
#define LOG2E   1.4426950408889634f

typedef float  f32x4  __attribute__((ext_vector_type(4)));
typedef int    i32x4  __attribute__((ext_vector_type(4)));
typedef short  s16x4  __attribute__((ext_vector_type(4)));
typedef __bf16 bf16x8 __attribute__((ext_vector_type(8)));

union FragI { i32x4 i; bf16x8 b; };

// pack two f32 into bf16x2 by truncation: ONE v_perm_b32.
__device__ inline int pack_bf16_trunc(float a, float b) {
  return (int)__builtin_amdgcn_perm(__builtin_bit_cast(unsigned, b),
                                    __builtin_bit_cast(unsigned, a),
                                    0x07060302u);
}

// ---------------------------------------------------------------------------
// fused prep: x->bf16 (rows padded to 272), qkv_w->bf16 (Q rows pre-scaled by
// SCALE*log2e), proj_w->bf16, keep-mask -> bias/keepi.
#define SEG_X 1048576
#define SEG_W (SEG_X + 196608)
#define SEG_P (SEG_W + 65536)
#define SEG_M (SEG_P + 4096)
__global__ __launch_bounds__(256) void fused_prep(const float* __restrict__ x,
                                                  const float* __restrict__ qkv_w,
                                                  const float* __restrict__ proj_w,
                                                  const float* __restrict__ dbz,
                                                  __bf16* __restrict__ xb,
                                                  __bf16* __restrict__ wqkvb,
                                                  __bf16* __restrict__ wprojb,
                                                  float* __restrict__ bias,
                                                  int* __restrict__ keepi) {
  int gid = blockIdx.x * 256 + threadIdx.x;
  if (gid < SEG_X) {
    xb[(gid >> 8) * XB_STRIDE + (gid & 255)] = (__bf16)x[gid];
  } else if (gid < SEG_W) {
    int i = gid - SEG_X;
    float s = ((i >> 8) < 256) ? (SCALE_F * LOG2E) : 1.0f;   // Q output rows
    wqkvb[(i >> 8) * XB_STRIDE + (i & 255)] = (__bf16)(qkv_w[i] * s);
  } else if (gid < SEG_P) {
    int i = gid - SEG_W;
    wprojb[(i >> 8) * XB_STRIDE + (i & 255)] = (__bf16)proj_w[i];
  } else if (gid < SEG_M) {
    int n = gid - SEG_P;
    int t = n >> 10, rc = n & 1023, r = rc >> 5, c = rc & 31;
    bool keep = false;
    #pragma unroll
    for (int dr = -1; dr <= 1; dr++)
      #pragma unroll
      for (int dc = -1; dc <= 1; dc++) {
        int rr = r + dr, cc = c + dc;
        if (rr >= 0 && rr < 32 && cc >= 0 && cc < 32)
          keep = keep || (dbz[t * 1024 + rr * 32 + cc] >= 15.0f);
      }
    bias[n]  = keep ? 0.0f : -30000.0f;   // exp2(s-30000) == 0 exactly
    keepi[n] = keep ? 1 : 0;
  }
}

// ---------------------------------------------------------------------------
// QKV GEMM, operand-swapped (D[channel][token]), software-pipelined k-loop.
// q,k -> [h][n][d]; v -> [h][d][VT_STRIDE] with keys SIGMA-PERMUTED within
// each 32-key group so the attention V fragment is ONE contiguous dwordx4.
__global__ __launch_bounds__(256) void qkv_gemm(const __bf16* __restrict__ xb,
                                                const __bf16* __restrict__ wb,
                                                __bf16* __restrict__ qb,
                                                __bf16* __restrict__ kb,
                                                __bf16* __restrict__ vt) {
  int wave = threadIdx.x >> 6, lane = threadIdx.x & 63;
  int quad = lane >> 4, l16 = lane & 15;
  int m0 = blockIdx.x * 64 + wave * 16;   // tokens
  int n0 = blockIdx.y * 64;               // output channels

  const __bf16* xrow = xb + (size_t)(m0 + l16) * XB_STRIDE + quad * 8;
  const __bf16* wrow = wb + (size_t)(n0 + l16) * XB_STRIDE + quad * 8;

  FragI xc, wc[4];
  xc.i = *(const i32x4*)(xrow);
  #pragma unroll
  for (int nt = 0; nt < 4; nt++)
    wc[nt].i = *(const i32x4*)(wrow + (size_t)nt * 16 * XB_STRIDE);

  f32x4 acc[4] = {};
  for (int kk = 0; kk < CDIM; kk += 32) {
    int kn = (kk + 32 < CDIM) ? kk + 32 : 0;      // last prefetch unused
    FragI xn, wn[4];
    xn.i = *(const i32x4*)(xrow + kn);
    #pragma unroll
    for (int nt = 0; nt < 4; nt++)
      wn[nt].i = *(const i32x4*)(wrow + (size_t)nt * 16 * XB_STRIDE + kn);
    #pragma unroll
    for (int nt = 0; nt < 4; nt++)
      acc[nt] = __builtin_amdgcn_mfma_f32_16x16x32_bf16(wc[nt].b, xc.b, acc[nt], 0, 0, 0);
    xc = xn;
    #pragma unroll
    for (int nt = 0; nt < 4; nt++) wc[nt] = wn[nt];
  }
  int m = m0 + l16;
  // sigma-permuted token index within its 32-key group (for V only)
  int mperm = (m & ~31) + ((l16 >> 2) * 8) + (l16 & 3) + ((m & 16) ? 4 : 0);
  #pragma unroll
  for (int nt = 0; nt < 4; nt++) {
    int cbase = n0 + nt * 16 + quad * 4;       // 4 consecutive channels
    int which = cbase >> 8, rem = cbase & 255, hd = rem >> 5, d0 = rem & 31;
    if (which < 2) {
      union { s16x4 s; __bf16 h[4]; } u;
      #pragma unroll
      for (int r = 0; r < 4; r++) u.h[r] = (__bf16)acc[nt][r];
      __bf16* dst = (which == 0 ? qb : kb) + ((size_t)hd * N_TOK + m) * HD + d0;
      *(s16x4*)dst = u.s;
    } else {
      #pragma unroll
      for (int r = 0; r < 4; r++)
        vt[(size_t)(hd * HD + d0 + r) * VT_STRIDE + mperm] = (__bf16)acc[nt][r];
    }
  }
}

// ---------------------------------------------------------------------------
// Attention v11: STAGE-SKEWED pipeline. 64-query blocks (R9 shape), 4 waves
// split keys. At iteration t: (1) K/bias loads for tile t+2, (2) S-MFMAs for
// tile t+1 (operands loaded 1 iter ago), (3) V loads for tile t+1,
// (4) exp/pack/PV for tile t using S computed a FULL ITERATION earlier --
// the VALU exp never reads an in-flight MFMA result (no RAW stall), and
// MFMA(t+1) executes concurrently with VALU(t) within the same wave.
// Slots: K(tile) in kslot[tile&1] (loads 2 ahead), V 1 ahead, S-stage
// ping-pong sa/sb[tile&1]. No-max exp2 softmax, bias in C, l via ones-MFMA.
__global__ __launch_bounds__(256, 2) void attn_kernel(const __bf16* __restrict__ qb,
                                                      const __bf16* __restrict__ kb,
                                                      const __bf16* __restrict__ vt,
                                                      const float* __restrict__ bias,
                                                      __bf16* __restrict__ ob) {
  __shared__ float red_o[4][64][34];
  __shared__ float red_l[4][64];

  int b = blockIdx.x;
  int head = b & 7, qx = b >> 3;       // 512 blocks = 2/CU; head%8 -> XCD affinity
  int wave = threadIdx.x >> 6, lane = threadIdx.x & 63;
  int quad = lane >> 4, l16 = lane & 15;
  int q0 = qx * 64;
  int kbase0 = wave * 32;

  const __bf16* qh = qb + (size_t)head * N_TOK * HD;
  const __bf16* kh = kb + (size_t)head * N_TOK * HD;
  const __bf16* vh = vt + (size_t)head * HD * VT_STRIDE;

  FragI qf[4];
  #pragma unroll
  for (int g = 0; g < 4; g++)
    qf[g].i = *(const i32x4*)(qh + (size_t)(q0 + g * 16 + l16) * HD + quad * 8);

  FragI ones;
  #pragma unroll
  for (int j = 0; j < 8; j++) ones.b[j] = (__bf16)1.0f;

  f32x4 o_lo[4] = {}, o_hi[4] = {}, lacc[4] = {};

  FragI ka[2], kx[2], vlo[2], vhi[2];
  f32x4 ba[2], bb[2];
  f32x4 sa[2][4], sb[2][4];

  // ---- prologue: K0/bias0 -> slot0, V0 -> vslot0, K1/bias1 -> slot1, S(0) ----
  {
    int k0 = kbase0;                    // tile 0
    ka[0].i = *(const i32x4*)(kh + (size_t)(k0 + l16) * HD + quad * 8);
    kx[0].i = *(const i32x4*)(kh + (size_t)(k0 + 16 + l16) * HD + quad * 8);
    ba[0] = *(const f32x4*)(bias + k0 + quad * 4);
    bb[0] = *(const f32x4*)(bias + k0 + 16 + quad * 4);
    vlo[0].i = *(const i32x4*)(vh + (size_t)l16 * VT_STRIDE + k0 + quad * 8);
    vhi[0].i = *(const i32x4*)(vh + (size_t)(16 + l16) * VT_STRIDE + k0 + quad * 8);
    int k1 = kbase0 + 128;              // tile 1
    ka[1].i = *(const i32x4*)(kh + (size_t)(k1 + l16) * HD + quad * 8);
    kx[1].i = *(const i32x4*)(kh + (size_t)(k1 + 16 + l16) * HD + quad * 8);
    ba[1] = *(const f32x4*)(bias + k1 + quad * 4);
    bb[1] = *(const f32x4*)(bias + k1 + 16 + quad * 4);
    #pragma unroll
    for (int g = 0; g < 4; g++) {
      sa[0][g] = __builtin_amdgcn_mfma_f32_16x16x32_bf16(ka[0].b, qf[g].b, ba[0], 0, 0, 0);
      sb[0][g] = __builtin_amdgcn_mfma_f32_16x16x32_bf16(kx[0].b, qf[g].b, bb[0], 0, 0, 0);
    }
  }

  #pragma unroll 4
  for (int t = 0; t < 32; t++) {
    int cur = t & 1, nxt = cur ^ 1;

    // (1) K/bias loads for tile t+2 into slot cur (K(t) is dead)
    int k2 = (t + 2 < 32) ? kbase0 + (t + 2) * 128 : kbase0;
    ka[cur].i = *(const i32x4*)(kh + (size_t)(k2 + l16) * HD + quad * 8);
    kx[cur].i = *(const i32x4*)(kh + (size_t)(k2 + 16 + l16) * HD + quad * 8);
    f32x4 ba2 = *(const f32x4*)(bias + k2 + quad * 4);
    f32x4 bb2 = *(const f32x4*)(bias + k2 + 16 + quad * 4);

    // (2) S-MFMAs for tile t+1 (operands arrived; result consumed next iter)
    #pragma unroll
    for (int g = 0; g < 4; g++) {
      sa[nxt][g] = __builtin_amdgcn_mfma_f32_16x16x32_bf16(ka[nxt].b, qf[g].b, ba[nxt], 0, 0, 0);
      sb[nxt][g] = __builtin_amdgcn_mfma_f32_16x16x32_bf16(kx[nxt].b, qf[g].b, bb[nxt], 0, 0, 0);
    }

    // (3) V loads for tile t+1 into vslot nxt (V(t-1) dead after last PV)
    int k1 = (t + 1 < 32) ? kbase0 + (t + 1) * 128 : kbase0;
    vlo[nxt].i = *(const i32x4*)(vh + (size_t)l16 * VT_STRIDE + k1 + quad * 8);
    vhi[nxt].i = *(const i32x4*)(vh + (size_t)(16 + l16) * VT_STRIDE + k1 + quad * 8);

    // stash t+2 bias after S-MFMA issue (ba[nxt] consumed by step 2)
    ba[cur] = ba2; bb[cur] = bb2;

    // (4) exp/pack/PV for tile t -- S(t) computed a full iteration ago
    FragI pf[4];
    #pragma unroll
    for (int g = 0; g < 4; g++) {
      float e0 = __builtin_amdgcn_exp2f(sa[cur][g][0]);
      float e1 = __builtin_amdgcn_exp2f(sa[cur][g][1]);
      float e2 = __builtin_amdgcn_exp2f(sa[cur][g][2]);
      float e3 = __builtin_amdgcn_exp2f(sa[cur][g][3]);
      float e4 = __builtin_amdgcn_exp2f(sb[cur][g][0]);
      float e5 = __builtin_amdgcn_exp2f(sb[cur][g][1]);
      float e6 = __builtin_amdgcn_exp2f(sb[cur][g][2]);
      float e7 = __builtin_amdgcn_exp2f(sb[cur][g][3]);
      pf[g].i[0] = pack_bf16_trunc(e0, e1);
      pf[g].i[1] = pack_bf16_trunc(e2, e3);
      pf[g].i[2] = pack_bf16_trunc(e4, e5);
      pf[g].i[3] = pack_bf16_trunc(e6, e7);
    }
    #pragma unroll
    for (int g = 0; g < 4; g++) {
      o_lo[g] = __builtin_amdgcn_mfma_f32_16x16x32_bf16(vlo[cur].b, pf[g].b, o_lo[g], 0, 0, 0);
      o_hi[g] = __builtin_amdgcn_mfma_f32_16x16x32_bf16(vhi[cur].b, pf[g].b, o_hi[g], 0, 0, 0);
      lacc[g] = __builtin_amdgcn_mfma_f32_16x16x32_bf16(ones.b, pf[g].b, lacc[g], 0, 0, 0);
    }
  }

  // ---- cross-wave reduction (one LDS round-trip) ----
  #pragma unroll
  for (int g = 0; g < 4; g++) {
    int q = g * 16 + l16;
    #pragma unroll
    for (int r = 0; r < 4; r++) {
      red_o[wave][q][quad * 4 + r]      = o_lo[g][r];
      red_o[wave][q][16 + quad * 4 + r] = o_hi[g][r];
    }
    if (quad == 0) red_l[wave][q] = lacc[g][0];  // all rows equal = l(q)
  }
  __syncthreads();

  // wave w reduces q-group g = w
  int q = wave * 16 + l16;
  float lt = red_l[0][q] + red_l[1][q] + red_l[2][q] + red_l[3][q];
  float inv = 1.0f / lt;
  f32x4 slo = {0.f, 0.f, 0.f, 0.f}, shi = {0.f, 0.f, 0.f, 0.f};
  #pragma unroll
  for (int src = 0; src < 4; src++) {
    #pragma unroll
    for (int r = 0; r < 4; r++) {
      slo[r] += red_o[src][q][quad * 4 + r];
      shi[r] += red_o[src][q][16 + quad * 4 + r];
    }
  }
  union { s16x4 s; __bf16 h[4]; } u1, u2;
  #pragma unroll
  for (int r = 0; r < 4; r++) {
    u1.h[r] = (__bf16)(slo[r] * inv);
    u2.h[r] = (__bf16)(shi[r] * inv);
  }
  __bf16* orow = ob + (size_t)(q0 + q) * XB_STRIDE + head * HD;
  *(s16x4*)(orow + quad * 4)      = u1.s;
  *(s16x4*)(orow + 16 + quad * 4) = u2.s;
}

// ---------------------------------------------------------------------------
// Output projection (pipelined): out = (keep ? attn@Wp^T + b : 0) + x
__global__ __launch_bounds__(256) void proj_gemm(const __bf16* __restrict__ ob,
                                                 const __bf16* __restrict__ wb,
                                                 const float* __restrict__ pb,
                                                 const int* __restrict__ keepi,
                                                 const float* __restrict__ x,
                                                 float* __restrict__ out) {
  int wave = threadIdx.x >> 6, lane = threadIdx.x & 63;
  int quad = lane >> 4, l16 = lane & 15;
  int m0 = blockIdx.x * 64 + wave * 16;
  int n0 = blockIdx.y * 64;

  const __bf16* arow = ob + (size_t)(m0 + l16) * XB_STRIDE + quad * 8;
  const __bf16* wrow = wb + (size_t)(n0 + l16) * XB_STRIDE + quad * 8;

  FragI ac, wc[4];
  ac.i = *(const i32x4*)(arow);
  #pragma unroll
  for (int nt = 0; nt < 4; nt++)
    wc[nt].i = *(const i32x4*)(wrow + (size_t)nt * 16 * XB_STRIDE);

  f32x4 acc[4] = {};
  for (int kk = 0; kk < CDIM; kk += 32) {
    int kn = (kk + 32 < CDIM) ? kk + 32 : 0;
    FragI an, wn[4];
    an.i = *(const i32x4*)(arow + kn);
    #pragma unroll
    for (int nt = 0; nt < 4; nt++)
      wn[nt].i = *(const i32x4*)(wrow + (size_t)nt * 16 * XB_STRIDE + kn);
    #pragma unroll
    for (int nt = 0; nt < 4; nt++)
      acc[nt] = __builtin_amdgcn_mfma_f32_16x16x32_bf16(wc[nt].b, ac.b, acc[nt], 0, 0, 0);
    ac = an;
    #pragma unroll
    for (int nt = 0; nt < 4; nt++) wc[nt] = wn[nt];
  }
  // D[channel][token]: row = channel quad*4+r, col = token l16
  int m = m0 + l16;
  int keep = keepi[m];
  #pragma unroll
  for (int nt = 0; nt < 4; nt++) {
    int c0 = n0 + nt * 16 + quad * 4;
    #pragma unroll
    for (int r = 0; r < 4; r++) {
      float v = acc[nt][r] + pb[c0 + r];
      v = keep ? v : 0.0f;
      out[(size_t)m * CDIM + c0 + r] = v + x[(size_t)m * CDIM + c0 + r];
    }
  }
}

// ---------------------------------------------------------------------------
extern "C" void kernel_launch(void* const* d_in, const int* in_sizes, int n_in,
                              void* d_out, int out_size, void* d_ws, size_t ws_size,
                              hipStream_t stream) {
  const float* x      = (const float*)d_in[0];
  const float* dbz    = (const float*)d_in[1];
  const float* qkv_w  = (const float*)d_in[2];
  const float* proj_w = (const float*)d_in[3];
  const float* proj_b = (const float*)d_in[4];
  float* out = (float*)d_out;

  char* w = (char*)d_ws;
  __bf16* xb     = (__bf16*)(w);                        // 4096x272x2 = 2.23MB
  __bf16* qb     = (__bf16*)(w + (3u << 20));           // 2MB
  __bf16* kb     = (__bf16*)(w + (5u << 20));           // 2MB
  __bf16* vt     = (__bf16*)(w + (7u << 20));           // 8*32*4128*2 = 2.02MB
  __bf16* ob     = (__bf16*)(w + (9u << 20) + (512u << 10));  // 2.23MB
  __bf16* wqkvb  = (__bf16*)(w + (12u << 20));          // 768x272x2 = 417KB
  __bf16* wprojb = (__bf16*)(w + (12u << 20) + (512u << 10)); // 139KB
  float*  bias   = (float*)(w + (13u << 20));           // 16KB
  int*    keepi  = (int*)(w + (13u << 20) + 16384);     // 16KB

  fused_prep<<<dim3(SEG_M / 256), dim3(256), 0, stream>>>(
      x, qkv_w, proj_w, dbz, xb, wqkvb, wprojb, bias, keepi);
  qkv_gemm<<<dim3(N_TOK / 64, QKV_N / 64), dim3(256), 0, stream>>>(
      xb, wqkvb, qb, kb, vt);
  attn_kernel<<<dim3((N_TOK / 64) * NH), dim3(256), 0, stream>>>(
      qb, kb, vt, bias, ob);
  proj_gemm<<<dim3(N_TOK / 64, CDIM / 64), dim3(256), 0, stream>>>(
      ob, wprojb, proj_b, keepi, x, out);
}